// Round 5
// baseline (329.060 us; speedup 1.0000x reference)
//
#include <hip/hip_runtime.h>

#define EPS 1e-5f

typedef float v2f __attribute__((ext_vector_type(2)));

constexpr int B = 32;
constexpr int H = 512;
constexpr int W = 512;
constexpr int NPIX = H * W;          // 262144
constexpr int P = 13;
constexpr int HP = H - P + 1;        // 500
constexpr int WP = W - P + 1;        // 500
constexpr int TILES_X = 8;           // 8 * 64 = 512 cols
constexpr int BAND_ROWS = 27;        // output rows per band; ITERS = 39 = 3*13
constexpr int BANDS_Y = 19;          // bands 0..17 -> rows 0..485; band 18 (y0=473) -> 486..499
constexpr int ITERS = BAND_ROWS + P - 1;   // 39

// ws layout (floats): gs[5][B] global moment sums, then ps[B] patch cc sums

// ---------------------------------------------------------------------------
// Fused kernel, one wave per block.
//  - __launch_bounds__(64,4): hard 128-VGPR cap -> 4 waves/SIMD (16/CU),
//    double R3's residency (R3: 240 VGPR from full 39-step unroll -> 8/CU).
//  - loop = unrolled 13-step fill + DYNAMIC outer loop over two 13-step
//    steady groups: ring slot stays compile-time (ring lives in registers,
//    65 VGPRs) but liveness can't inflate across the whole 39 steps.
//  - ONE __syncthreads() per row-step (cross-lane LDS without barrier is
//    compiler-level UB — R2 NaN). Double buffer makes barrier #2 redundant.
//  - moment chains packed as float2 -> v_pk ops; 2-deep global prefetch;
//    global-moment accumulation fused over owned region.
// grid = 32*8*19 = 4864 single-wave blocks (19/CU demand vs 16/CU resident)
// ---------------------------------------------------------------------------
__global__ __launch_bounds__(64, 4) void ncc_fused_kernel(
    const float* __restrict__ x1, const float* __restrict__ x2,
    float* __restrict__ gs, float* __restrict__ ps) {
  int bid = blockIdx.x;
  int b = bid / (TILES_X * BANDS_Y);
  int rem = bid % (TILES_X * BANDS_Y);
  int tile = rem % TILES_X;
  int band = rem / TILES_X;
  bool last = (band == BANDS_Y - 1);
  int x0 = tile * 64;
  int y0 = last ? (HP - BAND_ROWS) : band * BAND_ROWS;  // 473 for last band
  int tid = threadIdx.x;
  bool valid = (x0 + tid) < WP;
  bool halo = tid < 12;

  __shared__ v2f st[2][80];  // double-buffered row stage, 76 used, 1.28 KB

  const float* b1 = x1 + (size_t)b * NPIX + (size_t)y0 * W;
  const float* b2 = x2 + (size_t)b * NPIX + (size_t)y0 * W;
  int c = x0 + tid;                     // own column, always < 512
  int ch = min(x0 + 64 + tid, W - 1);   // halo column (clamped)
  int ylim = (H - 1) - y0;              // 38 for last band; >=52 otherwise

  // 2-deep prefetch pipeline: cur = row t, nxt = row t+1
  v2f cur, nxt, curh = {0.f, 0.f}, nxth = {0.f, 0.f};
  cur.x = b1[c];      cur.y = b2[c];
  nxt.x = b1[W + c];  nxt.y = b2[W + c];
  if (halo) {
    curh.x = b1[ch];     curh.y = b2[ch];
    nxth.x = b1[W + ch]; nxth.y = b2[W + ch];
  }

  // vertical ring in registers (slot is compile-time inside unrolled-13 body)
  v2f r_ab[13], r_sq[13];
  float r_x[13];
  v2f S_ab = {0.f, 0.f}, S_sq = {0.f, 0.f};
  float S_x = 0.f;
  v2f g_ab = {0.f, 0.f}, g_sq = {0.f, 0.f};
  float g_x = 0.f;
  float acc = 0.f;
  const float inv_n = 1.0f / 169.0f;

  auto step = [&](int t, int slot, bool fill) {
    int buf = t & 1;
    st[buf][tid] = cur;
    if (halo) st[buf][64 + tid] = curh;

    v2f my = cur;  // own-column value of row t (global stats)

    __syncthreads();  // staging visible to all lanes (compiler + HW order)

    // rotate pipeline, prefetch row t+2 (clamp binds only on last band tail)
    cur = nxt;
    curh = nxth;
    int yn = (t + 2 > ylim) ? ylim : (t + 2);
    nxt.x = b1[yn * W + c];
    nxt.y = b2[yn * W + c];
    if (halo) {
      nxth.x = b1[yn * W + ch];
      nxth.y = b2[yn * W + ch];
    }

    // global moments over owned rows
    // bands 0..17 own t<27; band 18 owns t>=13 (rows 486..511)
    bool owned = last ? (t >= 13) : (t < BAND_ROWS);
    if (owned) {
      g_ab += my;
      g_sq += my * my;
      g_x = fmaf(my.x, my.y, g_x);
    }

    // horizontal 13-tap sums (packed)
    v2f h_ab = {0.f, 0.f}, h_sq = {0.f, 0.f};
    float h_x = 0.f;
#pragma unroll
    for (int j = 0; j < P; ++j) {
      v2f v = st[buf][tid + j];
      h_ab += v;
      h_sq += v * v;
      h_x = fmaf(v.x, v.y, h_x);
    }

    // vertical sliding sum via register ring
    if (fill) {
      S_ab += h_ab; S_sq += h_sq; S_x += h_x;
    } else {
      S_ab += h_ab - r_ab[slot];
      S_sq += h_sq - r_sq[slot];
      S_x  += h_x  - r_x[slot];
    }
    r_ab[slot] = h_ab; r_sq[slot] = h_sq; r_x[slot] = h_x;

    // emit output row y0 + t - 12
    // last band: suppress t<=24 (rows 473..485 owned by band 17)
    bool do_out = fill ? (t == 12 && !last) : (!last || t >= 25);
    if (do_out) {
      v2f m = S_ab * inv_n;
      v2f vv = S_sq * inv_n - m * m;
      vv += EPS;
      float cross = fmaf(-S_ab.x * inv_n, S_ab.y, S_x);
      float cc = cross * rsqrtf(vv.x * vv.y);
      acc += valid ? cc : 0.f;
    }
  };

  // fill phase: 13 unrolled steps (slot = t)
#pragma unroll
  for (int u = 0; u < 13; ++u) step(u, u, true);

  // steady phase: dynamic outer loop (NOT unrolled) over two 13-step groups
#pragma clang loop unroll(disable)
  for (int g = 0; g < 2; ++g) {
    int tbase = 13 + g * 13;
#pragma unroll
    for (int u = 0; u < 13; ++u) step(tbase + u, u, false);
  }

  // wave reductions (single wave per block) + atomics
  float v0 = acc, v1 = g_ab.x, v2 = g_ab.y, v3 = g_sq.x, v4 = g_sq.y, v5 = g_x;
#pragma unroll
  for (int off = 32; off > 0; off >>= 1) {
    v0 += __shfl_down(v0, off, 64);
    v1 += __shfl_down(v1, off, 64);
    v2 += __shfl_down(v2, off, 64);
    v3 += __shfl_down(v3, off, 64);
    v4 += __shfl_down(v4, off, 64);
    v5 += __shfl_down(v5, off, 64);
  }
  if (tid == 0) {
    atomicAdd(&ps[b], v0);
    atomicAdd(&gs[0 * B + b], v1);
    atomicAdd(&gs[1 * B + b], v2);
    atomicAdd(&gs[2 * B + b], v3);
    atomicAdd(&gs[3 * B + b], v4);
    atomicAdd(&gs[4 * B + b], v5);
  }
}

// ---------------------------------------------------------------------------
// Combine: out[b] = 0.5*global_ncc + 0.5*patch_sum/(HP*WP*169)
// ---------------------------------------------------------------------------
__global__ void final_kernel(const float* __restrict__ gs,
                             const float* __restrict__ ps,
                             float* __restrict__ out) {
  int b = threadIdx.x;
  if (b < B) {
    float Nf = (float)NPIX;
    float s1 = gs[0 * B + b];
    float s2 = gs[1 * B + b];
    float s11 = gs[2 * B + b];
    float s22 = gs[3 * B + b];
    float s12 = gs[4 * B + b];
    float m1 = s1 / Nf;
    float m2 = s2 / Nf;
    float v1 = fmaf(-m1, m1, s11 / Nf);
    float v2 = fmaf(-m2, m2, s22 / Nf);
    float cross = fmaf(-Nf * m1, m2, s12);
    float g = cross * rsqrtf((v1 + EPS) * (v2 + EPS)) / Nf;
    float patch = ps[b] / ((float)HP * (float)WP * 169.0f);
    out[b] = 0.5f * g + 0.5f * patch;
  }
}

extern "C" void kernel_launch(void* const* d_in, const int* in_sizes, int n_in,
                              void* d_out, int out_size, void* d_ws, size_t ws_size,
                              hipStream_t stream) {
  const float* x1 = (const float*)d_in[0];
  const float* x2 = (const float*)d_in[1];
  float* out = (float*)d_out;
  float* gs = (float*)d_ws;        // 5*B floats
  float* ps = gs + 5 * B;          // B floats

  hipMemsetAsync(d_ws, 0, 6 * B * sizeof(float), stream);

  ncc_fused_kernel<<<B * TILES_X * BANDS_Y, 64, 0, stream>>>(x1, x2, gs, ps);
  final_kernel<<<1, 64, 0, stream>>>(gs, ps, out);
}

// Round 6
// 182.323 us; speedup vs baseline: 1.8048x; 1.8048x over previous
//
#include <hip/hip_runtime.h>

#define EPS 1e-5f

typedef float v2f __attribute__((ext_vector_type(2)));

constexpr int B = 32;
constexpr int H = 512;
constexpr int W = 512;
constexpr int NPIX = H * W;          // 262144
constexpr int P = 13;
constexpr int HP = H - P + 1;        // 500
constexpr int WP = W - P + 1;        // 500
constexpr int TILES_X = 8;           // 8 * 64 = 512 cols
constexpr int BAND_OUT = 27;         // output rows per band
constexpr int BANDS_Y = 19;          // 0..17 -> rows 0..485; band 18 (y0=473) -> 486..499
constexpr int G = 13;                // rows per staged group == ring depth (slot = u, compile-time)
constexpr int NGROUPS = 3;           // 39 input rows per band; y0=473+39=512 exactly -> no row clamp

// ws layout (floats): gs[5][B] global moment sums, then ps[B] patch cc sums

// ---------------------------------------------------------------------------
// Fused kernel, one wave per block. GEMM-style grouped K-loop:
//  - stage 13 rows x 2 images into LDS per barrier round (float4 global loads
//    on 19 lanes, interleaved (a,b) v2f layout via 2x ds_write_b128/row) —
//    ONE latency drain per 13 rows instead of per row (R1/R3: ~3000 cyc/row).
//  - 13 compute steps per group: pure LDS(b64) + packed-f32 VALU, ring slot
//    compile-time (u) because group size == ring depth; group loop DYNAMIC
//    so liveness can't inflate across 39 steps (R3: 240 VGPR).
//  - NO __launch_bounds__ waves arg (R4: cap -> 282 MB scratch spill).
//  - global-moment accumulation fused over owned rows (j==0 window read).
// grid = 32*8*19 = 4864 single-wave blocks.
// ---------------------------------------------------------------------------
__global__ __launch_bounds__(64) void ncc_fused_kernel(
    const float* __restrict__ x1, const float* __restrict__ x2,
    float* __restrict__ gs, float* __restrict__ ps) {
  const int bid = blockIdx.x;
  const int b    = bid / (TILES_X * BANDS_Y);
  const int rem  = bid % (TILES_X * BANDS_Y);
  const int tile = rem % TILES_X;
  const int band = rem / TILES_X;
  const bool last = (band == BANDS_Y - 1);
  const int x0 = tile * 64;
  const int y0 = last ? (HP - BAND_OUT) : band * BAND_OUT;  // 473 for last band
  const int tid = threadIdx.x;
  const bool valid = (x0 + tid) < WP;

  __shared__ v2f st[G][80];  // 13 rows x 76 used cols, interleaved (a,b); 8320 B

  const float* r1 = x1 + (size_t)b * NPIX + (size_t)y0 * W + x0;
  const float* r2 = x2 + (size_t)b * NPIX + (size_t)y0 * W + x0;

  // per-lane float4 staging offset (floats); clamp only binds for tile 7,
  // duplicating cols 508..511 into halo slots 64..75 -> only affects lanes
  // with col >= 500, which are masked by `valid`.
  int offf = tid * 4;
  { int mx = W - x0 - 4; if (offf > mx) offf = mx; }

  // vertical ring in registers (slot = u, compile-time in unrolled 13-step body)
  v2f r_ab[G], r_sq[G];
  float r_x[G];
  v2f S_ab = {0.f, 0.f}, S_sq = {0.f, 0.f};
  float S_x = 0.f;
  v2f g_ab = {0.f, 0.f}, g_sq = {0.f, 0.f};
  float g_x = 0.f;
  float acc = 0.f;
  const float inv_n = 1.0f / 169.0f;

  auto stage = [&](int g) {
    const float* p1 = r1 + (size_t)(g * G) * W;
    const float* p2 = r2 + (size_t)(g * G) * W;
    if (tid < 19) {  // 19 lanes x float4 = 76 floats per row per image
#pragma unroll
      for (int r = 0; r < G; ++r) {
        float4 a  = *(const float4*)(p1 + (size_t)r * W + offf);
        float4 bb = *(const float4*)(p2 + (size_t)r * W + offf);
        float4* d = (float4*)&st[r][tid * 4];
        d[0] = make_float4(a.x, bb.x, a.y, bb.y);
        d[1] = make_float4(a.z, bb.z, a.w, bb.w);
      }
    }
  };

  auto step = [&](int g, int u, bool fill) {
    const int t = g * G + u;  // wave-uniform

    // horizontal 13-tap sums (packed -> v_pk ops); own-col value from j==0
    v2f h_ab = {0.f, 0.f}, h_sq = {0.f, 0.f};
    float h_x = 0.f;
    v2f own = {0.f, 0.f};
#pragma unroll
    for (int j = 0; j < P; ++j) {
      v2f v = st[u][tid + j];
      if (j == 0) own = v;
      h_ab += v;
      h_sq += v * v;
      h_x = fmaf(v.x, v.y, h_x);
    }

    // global moments: bands 0..17 own rows t<27; band 18 owns t>=13 (486..511)
    bool owned = last ? (t >= G) : (t < BAND_OUT);
    if (owned) {
      g_ab += own;
      g_sq += own * own;
      g_x = fmaf(own.x, own.y, g_x);
    }

    // vertical sliding sum via register ring
    if (fill) {
      S_ab += h_ab; S_sq += h_sq; S_x += h_x;
    } else {
      S_ab += h_ab - r_ab[u];
      S_sq += h_sq - r_sq[u];
      S_x  += h_x  - r_x[u];
    }
    r_ab[u] = h_ab; r_sq[u] = h_sq; r_x[u] = h_x;

    // emit output row y0 + t - 12 (band 18 suppresses t<25: rows 473..485
    // already owned by band 17)
    bool do_out = (t >= 12) && (!last || t >= 25);
    if (do_out) {
      v2f m = S_ab * inv_n;
      v2f vv = S_sq * inv_n - m * m;
      vv += EPS;
      float cross = fmaf(-S_ab.x * inv_n, S_ab.y, S_x);
      float cc = cross * rsqrtf(vv.x * vv.y);
      acc += valid ? cc : 0.f;
    }
  };

  // group 0 (fill phase): stage, barrier, 13 unrolled steps
  stage(0);
  __syncthreads();
#pragma unroll
  for (int u = 0; u < G; ++u) step(0, u, true);

  // groups 1..2 (steady): DYNAMIC loop, compile-time slots inside
#pragma clang loop unroll(disable)
  for (int g = 1; g < NGROUPS; ++g) {
    __syncthreads();   // all lanes done reading st before overwrite
    stage(g);
    __syncthreads();   // staging visible (drains staging loads once per 13 rows)
#pragma unroll
    for (int u = 0; u < G; ++u) step(g, u, false);
  }

  // wave reductions (single wave per block) + atomics
  float v0 = acc, v1 = g_ab.x, v2 = g_ab.y, v3 = g_sq.x, v4 = g_sq.y, v5 = g_x;
#pragma unroll
  for (int off = 32; off > 0; off >>= 1) {
    v0 += __shfl_down(v0, off, 64);
    v1 += __shfl_down(v1, off, 64);
    v2 += __shfl_down(v2, off, 64);
    v3 += __shfl_down(v3, off, 64);
    v4 += __shfl_down(v4, off, 64);
    v5 += __shfl_down(v5, off, 64);
  }
  if (tid == 0) {
    atomicAdd(&ps[b], v0);
    atomicAdd(&gs[0 * B + b], v1);
    atomicAdd(&gs[1 * B + b], v2);
    atomicAdd(&gs[2 * B + b], v3);
    atomicAdd(&gs[3 * B + b], v4);
    atomicAdd(&gs[4 * B + b], v5);
  }
}

// ---------------------------------------------------------------------------
// Combine: out[b] = 0.5*global_ncc + 0.5*patch_sum/(HP*WP*169)
// ---------------------------------------------------------------------------
__global__ void final_kernel(const float* __restrict__ gs,
                             const float* __restrict__ ps,
                             float* __restrict__ out) {
  int b = threadIdx.x;
  if (b < B) {
    float Nf = (float)NPIX;
    float s1 = gs[0 * B + b];
    float s2 = gs[1 * B + b];
    float s11 = gs[2 * B + b];
    float s22 = gs[3 * B + b];
    float s12 = gs[4 * B + b];
    float m1 = s1 / Nf;
    float m2 = s2 / Nf;
    float v1 = fmaf(-m1, m1, s11 / Nf);
    float v2 = fmaf(-m2, m2, s22 / Nf);
    float cross = fmaf(-Nf * m1, m2, s12);
    float g = cross * rsqrtf((v1 + EPS) * (v2 + EPS)) / Nf;
    float patch = ps[b] / ((float)HP * (float)WP * 169.0f);
    out[b] = 0.5f * g + 0.5f * patch;
  }
}

extern "C" void kernel_launch(void* const* d_in, const int* in_sizes, int n_in,
                              void* d_out, int out_size, void* d_ws, size_t ws_size,
                              hipStream_t stream) {
  const float* x1 = (const float*)d_in[0];
  const float* x2 = (const float*)d_in[1];
  float* out = (float*)d_out;
  float* gs = (float*)d_ws;        // 5*B floats
  float* ps = gs + 5 * B;          // B floats

  hipMemsetAsync(d_ws, 0, 6 * B * sizeof(float), stream);

  ncc_fused_kernel<<<B * TILES_X * BANDS_Y, 64, 0, stream>>>(x1, x2, gs, ps);
  final_kernel<<<1, 64, 0, stream>>>(gs, ps, out);
}

// Round 7
// 126.313 us; speedup vs baseline: 2.6051x; 1.4434x over previous
//
#include <hip/hip_runtime.h>

#define EPS 1e-5f

typedef float v2f __attribute__((ext_vector_type(2)));

constexpr int B = 32;
constexpr int H = 512;
constexpr int W = 512;
constexpr int NPIX = H * W;          // 262144
constexpr int P = 13;
constexpr int HP = H - P + 1;        // 500
constexpr int WP = W - P + 1;        // 500
constexpr int TILES_X = 8;           // 8 * 64 = 512 cols
constexpr int BAND_OUT = 27;         // output rows per band
constexpr int BANDS_Y = 19;          // 0..17 -> rows 0..485; band 18 (y0=473) -> 486..499
constexpr int G = 13;                // rows per staged group == ring depth
constexpr int NGROUPS = 3;           // 39 input rows; y0=473+39=512 exactly -> no row clamp
constexpr int BLOCKS_PER_B = TILES_X * BANDS_Y;  // 152
constexpr int ROWF = 80;             // LDS row stride (76 used + 4 pad; DMA lanes 16..18 of
                                     // clamped tile land in pad, never next row)

// direct global->LDS DMA, 16 B per active lane, dst = uniform base + lane*16
#define GLOAD_LDS16(gp, lp)                                                    \
  __builtin_amdgcn_global_load_lds(                                            \
      (const __attribute__((address_space(1))) unsigned int*)(const void*)(gp),\
      (__attribute__((address_space(3))) unsigned int*)(void*)(lp), 16, 0, 0)

// ---------------------------------------------------------------------------
// Fused kernel, one wave per block. GEMM-style async-prefetch K-loop:
//  - global_load_lds width=16 stages 13 rows x 2 planes per group; group g+1
//    is DMA'd into the other buffer BEFORE computing group g, so the
//    end-of-group __syncthreads drains loads issued ~2600 cyc earlier
//    (R5 failure: synchronous stage exposed full load latency per group).
//  - planar LDS (DMA can't interleave); packed math by pairing along j:
//    6 v2f taps + 1 scalar per image -> same VALU as interleaved, and
//    stride-1 dword LDS reads = 2-way bank alias = free (R5: 758k conflicts
//    from 8B-stride b64 reads).
//  - vertical 13-deep ring in registers (slot = u, compile-time in unrolled
//    13-step body; group loop dynamic to stop liveness inflation — R3).
//  - per-block partials to ws (no atomics, no memset dispatch).
// grid = 32*8*19 = 4864 single-wave blocks.
// ---------------------------------------------------------------------------
__global__ __launch_bounds__(64) void ncc_fused_kernel(
    const float* __restrict__ x1, const float* __restrict__ x2,
    float* __restrict__ part) {
  const int bid = blockIdx.x;
  const int b    = bid / BLOCKS_PER_B;
  const int rem  = bid % BLOCKS_PER_B;
  const int tile = rem % TILES_X;
  const int band = rem / TILES_X;
  const bool last = (band == BANDS_Y - 1);
  const int x0 = tile * 64;
  const int y0 = last ? (HP - BAND_OUT) : band * BAND_OUT;  // 473 for last band
  const int tid = threadIdx.x;
  const bool valid = (x0 + tid) < WP;

  __shared__ float sa[2][G][ROWF];   // 8320 B
  __shared__ float sb[2][G][ROWF];   // 8320 B

  const float* r1 = x1 + (size_t)b * NPIX + (size_t)y0 * W + x0;
  const float* r2 = x2 + (size_t)b * NPIX + (size_t)y0 * W + x0;

  // loader geometry: 19 lanes x float4 = 76 floats/row/plane.
  // tile 7 halo clamp (cols >= 512 don't exist): lanes 16..18 reload cols
  // 508..511; their LDS slots (floats 64..75) feed only invalid lanes.
  int qoff = tid * 4;
  { int mx = W - x0 - 4; if (qoff > mx) qoff = mx; }
  const bool loader = tid < 19;

  auto stage = [&](int g, int buf) {
    if (loader) {
#pragma unroll
      for (int r = 0; r < G; ++r) {
        GLOAD_LDS16(r1 + (size_t)(g * G + r) * W + qoff, &sa[buf][r][0]);
        GLOAD_LDS16(r2 + (size_t)(g * G + r) * W + qoff, &sb[buf][r][0]);
      }
    }
  };

  // vertical ring in registers (slot = u, compile-time)
  float rh1[G], rh2[G], rh11[G], rh22[G], rh12[G];
  float S1 = 0.f, S2 = 0.f, S11 = 0.f, S22 = 0.f, S12 = 0.f;
  float g1 = 0.f, g2 = 0.f, g11 = 0.f, g22 = 0.f, g12 = 0.f;
  float acc = 0.f;
  const float inv_n = 1.0f / 169.0f;

  auto step = [&](int u, int buf, int t, bool fill) {
    const float* pa = &sa[buf][u][tid];
    const float* pb = &sb[buf][u][tid];
    v2f va[6], vb[6];
#pragma unroll
    for (int k = 0; k < 6; ++k) {
      va[k].x = pa[2 * k];     va[k].y = pa[2 * k + 1];
      vb[k].x = pb[2 * k];     vb[k].y = pb[2 * k + 1];
    }
    float a12 = pa[12], b12 = pb[12];

    // packed 13-tap sums (pairs along j)
    v2f h1v = va[0], h2v = vb[0];
    v2f h11v = va[0] * va[0], h22v = vb[0] * vb[0], h12v = va[0] * vb[0];
#pragma unroll
    for (int k = 1; k < 6; ++k) {
      h1v += va[k];
      h2v += vb[k];
      h11v += va[k] * va[k];
      h22v += vb[k] * vb[k];
      h12v += va[k] * vb[k];
    }
    float h1 = h1v.x + h1v.y + a12;
    float h2 = h2v.x + h2v.y + b12;
    float h11 = fmaf(a12, a12, h11v.x + h11v.y);
    float h22 = fmaf(b12, b12, h22v.x + h22v.y);
    float h12 = fmaf(a12, b12, h12v.x + h12v.y);

    // global moments from own column (tap j=0):
    // bands 0..17 own rows t<27; band 18 owns t>=13 (rows 486..511)
    bool owned = last ? (t >= G) : (t < BAND_OUT);
    if (owned) {
      float a0 = va[0].x, b0 = vb[0].x;
      g1 += a0; g2 += b0;
      g11 = fmaf(a0, a0, g11);
      g22 = fmaf(b0, b0, g22);
      g12 = fmaf(a0, b0, g12);
    }

    // vertical sliding sum via register ring
    if (fill) {
      S1 += h1; S2 += h2; S11 += h11; S22 += h22; S12 += h12;
    } else {
      S1 += h1 - rh1[u]; S2 += h2 - rh2[u];
      S11 += h11 - rh11[u]; S22 += h22 - rh22[u]; S12 += h12 - rh12[u];
    }
    rh1[u] = h1; rh2[u] = h2; rh11[u] = h11; rh22[u] = h22; rh12[u] = h12;

    // emit output row y0 + t - 12 (band 18 suppresses t<25: rows 473..485
    // owned by band 17)
    if (t >= 12 && (!last || t >= 25)) {
      float m1 = S1 * inv_n, m2 = S2 * inv_n;
      float vv1 = fmaf(-m1, m1, S11 * inv_n) + EPS;
      float vv2 = fmaf(-m2, m2, S22 * inv_n) + EPS;
      float cross = fmaf(-S1 * inv_n, S2, S12);
      float cc = cross * rsqrtf(vv1 * vv2);
      acc += valid ? cc : 0.f;
    }
  };

  // prologue: stage group 0, drain, then launch async prefetch of group 1
  stage(0, 0);
  __syncthreads();            // drains DMA(0) — the only exposed load latency
  stage(1, 1);                // in flight during fill compute

#pragma unroll
  for (int u = 0; u < G; ++u) step(u, 0, u, true);
  __syncthreads();            // drains DMA(1), already landed

#pragma clang loop unroll(disable)
  for (int g = 1; g < NGROUPS; ++g) {
    if (g + 1 < NGROUPS) stage(g + 1, (g + 1) & 1);  // async into free buffer
    const int buf = g & 1;
#pragma unroll
    for (int u = 0; u < G; ++u) step(u, buf, g * G + u, false);
    __syncthreads();          // drains prefetch issued before this group
  }

  // wave-reduce 6 partials, lane 0 writes block slot (no atomics)
  float v0 = acc, v1 = g1, v2 = g2, v3 = g11, v4 = g22, v5 = g12;
#pragma unroll
  for (int off = 32; off > 0; off >>= 1) {
    v0 += __shfl_down(v0, off, 64);
    v1 += __shfl_down(v1, off, 64);
    v2 += __shfl_down(v2, off, 64);
    v3 += __shfl_down(v3, off, 64);
    v4 += __shfl_down(v4, off, 64);
    v5 += __shfl_down(v5, off, 64);
  }
  if (tid == 0) {
    float* o = part + (size_t)bid * 6;
    o[0] = v0; o[1] = v1; o[2] = v2; o[3] = v3; o[4] = v4; o[5] = v5;
  }
}

// ---------------------------------------------------------------------------
// Reduce per-block partials; one block per batch.
// out[b] = 0.5*global_ncc + 0.5*patch_sum/(HP*WP*169)
// ---------------------------------------------------------------------------
__global__ __launch_bounds__(64) void final_kernel(
    const float* __restrict__ part, float* __restrict__ out) {
  int b = blockIdx.x;
  int tid = threadIdx.x;
  float s[6] = {0.f, 0.f, 0.f, 0.f, 0.f, 0.f};
  for (int i = tid; i < BLOCKS_PER_B; i += 64) {
    const float* p = part + (size_t)(b * BLOCKS_PER_B + i) * 6;
#pragma unroll
    for (int k = 0; k < 6; ++k) s[k] += p[k];
  }
#pragma unroll
  for (int off = 32; off > 0; off >>= 1) {
#pragma unroll
    for (int k = 0; k < 6; ++k) s[k] += __shfl_down(s[k], off, 64);
  }
  if (tid == 0) {
    float Nf = (float)NPIX;
    float m1 = s[1] / Nf;
    float m2 = s[2] / Nf;
    float v1 = fmaf(-m1, m1, s[3] / Nf);
    float v2 = fmaf(-m2, m2, s[4] / Nf);
    float cross = fmaf(-Nf * m1, m2, s[5]);
    float g = cross * rsqrtf((v1 + EPS) * (v2 + EPS)) / Nf;
    float patch = s[0] / ((float)HP * (float)WP * 169.0f);
    out[b] = 0.5f * g + 0.5f * patch;
  }
}

extern "C" void kernel_launch(void* const* d_in, const int* in_sizes, int n_in,
                              void* d_out, int out_size, void* d_ws, size_t ws_size,
                              hipStream_t stream) {
  const float* x1 = (const float*)d_in[0];
  const float* x2 = (const float*)d_in[1];
  float* out = (float*)d_out;
  float* part = (float*)d_ws;   // 4864 * 6 floats = 114 KiB; every slot written

  ncc_fused_kernel<<<B * BLOCKS_PER_B, 64, 0, stream>>>(x1, x2, part);
  final_kernel<<<B, 64, 0, stream>>>(part, out);
}

// Round 8
// 122.281 us; speedup vs baseline: 2.6910x; 1.0330x over previous
//
#include <hip/hip_runtime.h>

#define EPS 1e-5f

typedef float v2f __attribute__((ext_vector_type(2)));

constexpr int B = 32;
constexpr int H = 512;
constexpr int W = 512;
constexpr int NPIX = H * W;          // 262144
constexpr int P = 13;
constexpr int HP = H - P + 1;        // 500
constexpr int WP = W - P + 1;        // 500
constexpr int TILES_X = 4;           // 128 output cols per tile, 2 per lane
constexpr int BAND_OUT = 40;         // output rows per band
constexpr int BANDS_Y = 13;          // bands 0..11 -> rows 0..479; band 12 (y0=460) -> 480..499
constexpr int G = 13;                // rows per staged group == ring depth
constexpr int NGROUPS = 4;           // 52 input rows; 460+52=512 exactly -> no row clamp
constexpr int ITER_LAST_OWN = 20;    // band 12 owns rows 480..511 -> t >= 20
constexpr int ITER_LAST_EMIT = 32;   // band 12 emits rows 480..499 -> t >= 32
constexpr int BLOCKS_PER_B = TILES_X * BANDS_Y;  // 52
constexpr int RS = 140;              // LDS row stride: 128 cols + 12 halo (35 lanes x 16B DMA)

// direct global->LDS DMA, 16 B per active lane, dst = uniform base + lane*16
#define GLOAD_LDS16(gp, lp)                                                    \
  __builtin_amdgcn_global_load_lds(                                            \
      (const __attribute__((address_space(1))) unsigned int*)(const void*)(gp),\
      (__attribute__((address_space(3))) unsigned int*)(void*)(lp), 16, 0, 0)

// ---------------------------------------------------------------------------
// Fused kernel, one wave per block, 2 output cols per lane (c0=x0+2*tid, c1=c0+1).
//  - R6's async global_load_lds double-buffered group staging kept verbatim
//    (it removed the load-latency stall: VALUBusy 22->45%, conflicts 758k->0).
//  - 2-col sharing: c1's 13-tap sums derived from c0's with one sub/add per
//    quantity -> VALU/output ~75 -> ~48 instr, LDS reads/output 14 -> 7.
//    Taps load as clean 8B-aligned ds_read_b64 (lane base = float 2*tid).
//  - BAND_OUT 40: vertical halo redundancy 52/40 = 1.3x (was 39/27 = 1.44x).
//  - ring = 13 x 5 x v2f = 130 VGPR; group loop dynamic (R3 lesson), no
//    launch_bounds waves cap (R4 lesson). Spill tripwire: WRITE_SIZE.
// grid = 32*4*13 = 1664 single-wave blocks; LDS 29.1 KB -> 5 blocks/CU.
// ---------------------------------------------------------------------------
__global__ __launch_bounds__(64) void ncc_fused_kernel(
    const float* __restrict__ x1, const float* __restrict__ x2,
    float* __restrict__ part) {
  const int bid = blockIdx.x;
  const int b    = bid / BLOCKS_PER_B;
  const int rem  = bid % BLOCKS_PER_B;
  const int tile = rem % TILES_X;
  const int band = rem / TILES_X;
  const bool last = (band == BANDS_Y - 1);
  const int x0 = tile * 128;
  const int y0 = last ? (HP - BAND_OUT) : band * BAND_OUT;  // 460 for last band
  const int tid = threadIdx.x;
  const int c0 = x0 + 2 * tid;
  const bool valid0 = c0 < WP;
  const bool valid1 = (c0 + 1) < WP;

  __shared__ float sa[2][G][RS];   // 14560 B
  __shared__ float sb[2][G][RS];   // 14560 B

  const float* r1 = x1 + (size_t)b * NPIX + (size_t)y0 * W + x0;
  const float* r2 = x2 + (size_t)b * NPIX + (size_t)y0 * W + x0;

  // loader: 35 lanes x float4 = 140 floats/row/plane. Tile 3 clamp: lanes
  // 32..34 re-read cols 508..511 into LDS floats 128..139, consumed only by
  // out-cols >= 500 (masked). DMA dst is lane-indexed: base + lane*16.
  int qoff = tid * 4;
  { int mx = W - x0 - 4; if (qoff > mx) qoff = mx; }
  const bool loader = tid < 35;

  auto stage = [&](int g, int buf) {
    if (loader) {
#pragma unroll
      for (int r = 0; r < G; ++r) {
        GLOAD_LDS16(r1 + (size_t)(g * G + r) * W + qoff, &sa[buf][r][0]);
        GLOAD_LDS16(r2 + (size_t)(g * G + r) * W + qoff, &sb[buf][r][0]);
      }
    }
  };

  // vertical ring in registers, v2f across the lane's 2 cols (slot = u)
  v2f rr1[G], rr2[G], rr11[G], rr22[G], rr12[G];
  v2f S1 = {0.f, 0.f}, S2 = {0.f, 0.f}, S11 = {0.f, 0.f}, S22 = {0.f, 0.f},
      S12 = {0.f, 0.f};
  v2f g1 = {0.f, 0.f}, g2 = {0.f, 0.f}, g11 = {0.f, 0.f}, g22 = {0.f, 0.f},
      g12 = {0.f, 0.f};
  float acc = 0.f;
  const float inv_n = 1.0f / 169.0f;

  auto step = [&](int u, int buf, int t, bool fill) {
    const float* pa = &sa[buf][u][2 * tid];
    const float* pb = &sb[buf][u][2 * tid];
    v2f A[7], Bv[7];
#pragma unroll
    for (int k = 0; k < 7; ++k) {
      A[k] = *(const v2f*)(pa + 2 * k);   // 8B-aligned ds_read_b64
      Bv[k] = *(const v2f*)(pb + 2 * k);
    }

    // c0 window = floats 0..12; c1 window = floats 1..13 (A[6].y is tap 13)
    v2f q11 = A[0] * A[0], q22 = Bv[0] * Bv[0], q12 = A[0] * Bv[0];
    v2f h1v = A[0], h2v = Bv[0], h11v = q11, h22v = q22, h12v = q12;
#pragma unroll
    for (int k = 1; k < 6; ++k) {
      h1v += A[k];
      h2v += Bv[k];
      h11v += A[k] * A[k];
      h22v += Bv[k] * Bv[k];
      h12v += A[k] * Bv[k];
    }
    float a12 = A[6].x, b12 = Bv[6].x, a13 = A[6].y, b13 = Bv[6].y;
    float h1_0 = h1v.x + h1v.y + a12;
    float h2_0 = h2v.x + h2v.y + b12;
    float h11_0 = fmaf(a12, a12, h11v.x + h11v.y);
    float h22_0 = fmaf(b12, b12, h22v.x + h22v.y);
    float h12_0 = fmaf(a12, b12, h12v.x + h12v.y);
    // incremental shift for c1
    v2f h1 = {h1_0, h1_0 - A[0].x + a13};
    v2f h2 = {h2_0, h2_0 - Bv[0].x + b13};
    v2f h11 = {h11_0, fmaf(a13, a13, h11_0 - q11.x)};
    v2f h22 = {h22_0, fmaf(b13, b13, h22_0 - q22.x)};
    v2f h12 = {h12_0, fmaf(a13, b13, h12_0 - q12.x)};

    // global moments: own cols (c0,c1) = A[0]/Bv[0] as v2f; squares reused
    bool owned = last ? (t >= ITER_LAST_OWN) : (t < BAND_OUT);
    if (owned) {
      g1 += A[0]; g2 += Bv[0]; g11 += q11; g22 += q22; g12 += q12;
    }

    // vertical sliding sums via register ring
    if (fill) {
      S1 += h1; S2 += h2; S11 += h11; S22 += h22; S12 += h12;
    } else {
      S1 += h1 - rr1[u]; S2 += h2 - rr2[u];
      S11 += h11 - rr11[u]; S22 += h22 - rr22[u]; S12 += h12 - rr12[u];
    }
    rr1[u] = h1; rr2[u] = h2; rr11[u] = h11; rr22[u] = h22; rr12[u] = h12;

    // emit output row y0 + t - 12 (band 12 suppresses rows < 480)
    bool do_out = (t >= 12) && (!last || t >= ITER_LAST_EMIT);
    if (do_out) {
      v2f m1 = S1 * inv_n, m2 = S2 * inv_n;
      v2f vv1 = S11 * inv_n - m1 * m1 + EPS;
      v2f vv2 = S22 * inv_n - m2 * m2 + EPS;
      v2f cross = S12 - (S1 * inv_n) * S2;
      v2f den = vv1 * vv2;
      float cc0 = cross.x * rsqrtf(den.x);
      float cc1 = cross.y * rsqrtf(den.y);
      acc += (valid0 ? cc0 : 0.f) + (valid1 ? cc1 : 0.f);
    }
  };

  // prologue: stage group 0, drain, launch async prefetch of group 1
  stage(0, 0);
  __syncthreads();            // drains DMA(0) — only exposed load latency
  stage(1, 1);                // in flight during fill compute

#pragma unroll
  for (int u = 0; u < G; ++u) step(u, 0, u, true);
  __syncthreads();            // drains DMA(1), long since landed

#pragma clang loop unroll(disable)
  for (int g = 1; g < NGROUPS; ++g) {
    if (g + 1 < NGROUPS) stage(g + 1, (g + 1) & 1);  // async into free buffer
    const int buf = g & 1;
#pragma unroll
    for (int u = 0; u < G; ++u) step(u, buf, g * G + u, false);
    __syncthreads();          // drains prefetch issued before this group
  }

  // fold v2f col-pairs, wave-reduce 6 scalars, lane 0 writes block slot
  float v0 = acc;
  float w1 = g1.x + g1.y, w2 = g2.x + g2.y;
  float w3 = g11.x + g11.y, w4 = g22.x + g22.y, w5 = g12.x + g12.y;
#pragma unroll
  for (int off = 32; off > 0; off >>= 1) {
    v0 += __shfl_down(v0, off, 64);
    w1 += __shfl_down(w1, off, 64);
    w2 += __shfl_down(w2, off, 64);
    w3 += __shfl_down(w3, off, 64);
    w4 += __shfl_down(w4, off, 64);
    w5 += __shfl_down(w5, off, 64);
  }
  if (tid == 0) {
    float* o = part + (size_t)bid * 6;
    o[0] = v0; o[1] = w1; o[2] = w2; o[3] = w3; o[4] = w4; o[5] = w5;
  }
}

// ---------------------------------------------------------------------------
// Reduce per-block partials; one block per batch.
// out[b] = 0.5*global_ncc + 0.5*patch_sum/(HP*WP*169)
// ---------------------------------------------------------------------------
__global__ __launch_bounds__(64) void final_kernel(
    const float* __restrict__ part, float* __restrict__ out) {
  int b = blockIdx.x;
  int tid = threadIdx.x;
  float s[6] = {0.f, 0.f, 0.f, 0.f, 0.f, 0.f};
  for (int i = tid; i < BLOCKS_PER_B; i += 64) {
    const float* p = part + (size_t)(b * BLOCKS_PER_B + i) * 6;
#pragma unroll
    for (int k = 0; k < 6; ++k) s[k] += p[k];
  }
#pragma unroll
  for (int off = 32; off > 0; off >>= 1) {
#pragma unroll
    for (int k = 0; k < 6; ++k) s[k] += __shfl_down(s[k], off, 64);
  }
  if (tid == 0) {
    float Nf = (float)NPIX;
    float m1 = s[1] / Nf;
    float m2 = s[2] / Nf;
    float v1 = fmaf(-m1, m1, s[3] / Nf);
    float v2 = fmaf(-m2, m2, s[4] / Nf);
    float cross = fmaf(-Nf * m1, m2, s[5]);
    float g = cross * rsqrtf((v1 + EPS) * (v2 + EPS)) / Nf;
    float patch = s[0] / ((float)HP * (float)WP * 169.0f);
    out[b] = 0.5f * g + 0.5f * patch;
  }
}

extern "C" void kernel_launch(void* const* d_in, const int* in_sizes, int n_in,
                              void* d_out, int out_size, void* d_ws, size_t ws_size,
                              hipStream_t stream) {
  const float* x1 = (const float*)d_in[0];
  const float* x2 = (const float*)d_in[1];
  float* out = (float*)d_out;
  float* part = (float*)d_ws;   // 1664 * 6 floats = 39 KiB; every slot written

  ncc_fused_kernel<<<B * BLOCKS_PER_B, 64, 0, stream>>>(x1, x2, part);
  final_kernel<<<B, 64, 0, stream>>>(part, out);
}